// Round 2
// baseline (1155.441 us; speedup 1.0000x reference)
//
#include <hip/hip_runtime.h>
#include <hip/hip_bf16.h>
#include <hip/hip_fp16.h>

// SimpleRNN: B=64, S=2048, IN=256, H=128, OUT=3 (all fp32)
// Phase 1: xproj = x @ W_xh^T + b_xh via f16 MFMA (byte-identical to r10,
//   ~205 us; structure-bound, not ALU-bound -- to be attacked separately).
// Phase 2 (r11): scan rewritten 8-waves -> ONE WAVE per batch, ZERO barriers.
//   r9/r10 spent ~650 of 686 cyc/step on the 8-wave s_barrier + ds_read
//   latency + quad-reduce. Now: lane j owns rows 2j,2j+1 (W_hh in 128 half2
//   VGPRs), h (256 B f16) broadcast-read from LDS (same-address ds_read_b128
//   = conflict-free broadcast), wave-synchronous lgkmcnt(0) only.
//   Serial chain/step ~= 128 v_dot2 issue (~260 cy) + write-wait + tanh.

#define RNN_B   64
#define RNN_S   2048
#define RNN_IN  256
#define RNN_H   128
#define RNN_OUT 3

typedef _Float16 half2v __attribute__((ext_vector_type(2)));
typedef _Float16 half4 __attribute__((ext_vector_type(4)));
typedef _Float16 half8 __attribute__((ext_vector_type(8)));
typedef float f32x4 __attribute__((ext_vector_type(4)));

#if __has_builtin(__builtin_amdgcn_fdot2)
#define FDOT2(a, b, c) __builtin_amdgcn_fdot2((a), (b), (c), false)
#else
#define FDOT2(a, b, c) \
  fmaf((float)(a).x, (float)(b).x, fmaf((float)(a).y, (float)(b).y, (c)))
#endif

// ---------------------------------------------------------------------------
// Phase 1: f16 MFMA GEMM  C[M=131072, N=128] = A[M,256] * B[128,256]^T + bias
// (byte-identical to round 1 for attribution)
// ---------------------------------------------------------------------------
__global__ __launch_bounds__(256) void xproj_mfma(
    const float* __restrict__ x, const float* __restrict__ Wxh,
    const float* __restrict__ bxh, float* __restrict__ xp) {
  __shared__ __align__(16) _Float16 Ash[128][40];
  __shared__ __align__(16) _Float16 Bsh[128][40];

  const int tid = threadIdx.x;
  const int m0 = blockIdx.x * 128;
  const int wv = tid >> 6;
  const int lane = tid & 63;
  const int wr = wv >> 1;          // wave row (0..1) -> M offset 64*wr
  const int wc = wv & 1;           // wave col (0..1) -> N offset 64*wc
  const int fr = lane & 15;        // fragment row/col index
  const int fk = lane >> 4;        // k-group 0..3

  const int lr = tid >> 3;         // row 0..31 (+32*p)
  const int lc = (tid & 7) * 4;    // k-col 0..28 within 32-chunk

  f32x4 acc[4][4];
#pragma unroll
  for (int m = 0; m < 4; ++m)
#pragma unroll
    for (int n = 0; n < 4; ++n) {
      acc[m][n][0] = 0.f; acc[m][n][1] = 0.f;
      acc[m][n][2] = 0.f; acc[m][n][3] = 0.f;
    }

  for (int kc = 0; kc < RNN_IN; kc += 32) {
#pragma unroll
    for (int p = 0; p < 4; ++p) {
      const int row = lr + 32 * p;
      const float4 va = *(const float4*)&x[(size_t)(m0 + row) * RNN_IN + kc + lc];
      half4 ha;
      ha.x = (_Float16)va.x; ha.y = (_Float16)va.y;
      ha.z = (_Float16)va.z; ha.w = (_Float16)va.w;
      *(half4*)&Ash[row][lc] = ha;
      const float4 vb = *(const float4*)&Wxh[(size_t)row * RNN_IN + kc + lc];
      half4 hb;
      hb.x = (_Float16)vb.x; hb.y = (_Float16)vb.y;
      hb.z = (_Float16)vb.z; hb.w = (_Float16)vb.w;
      *(half4*)&Bsh[row][lc] = hb;
    }
    __syncthreads();

    half8 af[4], bf[4];
#pragma unroll
    for (int m = 0; m < 4; ++m)
      af[m] = *(const half8*)&Ash[wr * 64 + m * 16 + fr][fk * 8];
#pragma unroll
    for (int n = 0; n < 4; ++n)
      bf[n] = *(const half8*)&Bsh[wc * 64 + n * 16 + fr][fk * 8];
#pragma unroll
    for (int m = 0; m < 4; ++m)
#pragma unroll
      for (int n = 0; n < 4; ++n)
        acc[m][n] = __builtin_amdgcn_mfma_f32_16x16x32_f16(
            af[m], bf[n], acc[m][n], 0, 0, 0);
    __syncthreads();
  }

  float bb[4];
#pragma unroll
  for (int n = 0; n < 4; ++n) bb[n] = bxh[wc * 64 + n * 16 + fr];
#pragma unroll
  for (int m = 0; m < 4; ++m) {
    const size_t rbase = (size_t)(m0 + wr * 64 + m * 16 + 4 * fk);
#pragma unroll
    for (int reg = 0; reg < 4; ++reg) {
      float* rowp = &xp[(rbase + reg) * RNN_H];
#pragma unroll
      for (int n = 0; n < 4; ++n)
        rowp[wc * 64 + n * 16 + fr] = acc[m][n][reg] + bb[n];
    }
  }
}

// fast tanh: 1 - 2/(exp(2x)+1); saturates correctly at +-inf
__device__ __forceinline__ float fast_tanh(float a) {
  const float e = __expf(2.f * a);
  return 1.f - 2.f / (e + 1.f);
}

// ---------------------------------------------------------------------------
// Phase 2: recurrence, ONE WAVE per batch (grid=64 blocks x 64 threads).
// Lane j owns rows 2j, 2j+1: W_hh[2j,:] and W_hh[2j+1,:] as 128 half2 VGPRs.
// h (128 f16 = 256 B) in LDS; each step every lane broadcast-reads all of h
// (16x ds_read_b128, uniform address = conflict-free broadcast), computes two
// full-row dots (128 v_dot2, fp32 acc, 4-way interleaved chains), tanh, and
// writes its packed half2 back.  NO s_barrier anywhere: single-wave lockstep
// + s_waitcnt lgkmcnt(0) after the write is the only synchronization.
// ---------------------------------------------------------------------------

// one recurrence step; leaves fp32 h values in hfA/hfB (used by final FC)
#define RNN_STEP1(PREG, TNEXT)                                        \
  {                                                                   \
    const float xin0 = PREG.x, xin1 = PREG.y;                         \
    PREG = *(const float2*)&xpb[(size_t)(TNEXT) * RNN_H];             \
    float accA[4] = {0.f, 0.f, 0.f, 0.f};                             \
    float accB[4] = {0.f, 0.f, 0.f, 0.f};                             \
    const float4* hv4 = (const float4*)hs;                            \
    _Pragma("unroll")                                                 \
    for (int c = 0; c < 4; ++c) {                                     \
      union { float4 f4[4]; half2v h[16]; } u;                        \
      u.f4[0] = hv4[4 * c + 0];                                       \
      u.f4[1] = hv4[4 * c + 1];                                       \
      u.f4[2] = hv4[4 * c + 2];                                       \
      u.f4[3] = hv4[4 * c + 3];                                       \
      _Pragma("unroll")                                               \
      for (int i = 0; i < 16; ++i) {                                  \
        accA[i & 3] = FDOT2(wA[16 * c + i], u.h[i], accA[i & 3]);     \
        accB[i & 3] = FDOT2(wB[16 * c + i], u.h[i], accB[i & 3]);     \
      }                                                               \
    }                                                                 \
    const float sA = (accA[0] + accA[1]) + (accA[2] + accA[3]);       \
    const float sB = (accB[0] + accB[1]) + (accB[2] + accB[3]);       \
    hfA = fast_tanh(biasA + xin0 + sA);                               \
    hfB = fast_tanh(biasB + xin1 + sB);                               \
    half2v hn;                                                        \
    hn.x = (_Float16)hfA;                                             \
    hn.y = (_Float16)hfB;                                             \
    *(half2v*)&hs[2 * j] = hn;                                        \
    asm volatile("s_waitcnt lgkmcnt(0)" ::: "memory");                \
  }

__global__ __launch_bounds__(64) void rnn_scan(
    const float* __restrict__ xp, const float* __restrict__ Whh,
    const float* __restrict__ bhh, const float* __restrict__ bh,
    const float* __restrict__ Wfc, const float* __restrict__ bfc,
    float* __restrict__ out) {
  const int b = blockIdx.x;
  const int j = threadIdx.x;          // lane 0..63

  __shared__ __align__(16) _Float16 hs[RNN_H];   // 256 B, single buffer
  __shared__ float fcred[RNN_OUT][64];           // FC partial reduce

  // W_hh rows 2j, 2j+1 -> 128 half2 registers (f16), fully unrolled/static
  half2v wA[64], wB[64];
  const float* rowA = &Whh[(size_t)(2 * j) * RNN_H];
  const float* rowB = rowA + RNN_H;
#pragma unroll
  for (int i = 0; i < 32; ++i) {
    const float4 fa = *(const float4*)&rowA[4 * i];
    const float4 fb = *(const float4*)&rowB[4 * i];
    half2v t0; t0.x = (_Float16)fa.x; t0.y = (_Float16)fa.y; wA[2 * i] = t0;
    half2v t1; t1.x = (_Float16)fa.z; t1.y = (_Float16)fa.w; wA[2 * i + 1] = t1;
    half2v s0; s0.x = (_Float16)fb.x; s0.y = (_Float16)fb.y; wB[2 * i] = s0;
    half2v s1; s1.x = (_Float16)fb.z; s1.y = (_Float16)fb.w; wB[2 * i + 1] = s1;
  }

  const float biasA = bhh[2 * j] + bh[2 * j];
  const float biasB = bhh[2 * j + 1] + bh[2 * j + 1];

  // zero h (64 lanes x 4 B = 256 B)
  ((float*)hs)[j] = 0.f;
  asm volatile("s_waitcnt lgkmcnt(0)" ::: "memory");

  const float* xpb = xp + (size_t)b * RNN_S * RNN_H + 2 * j;

  // 4-deep prefetch of xproj pairs (float2, coalesced 512 B/wave)
  float2 p0 = *(const float2*)&xpb[0 * RNN_H];
  float2 p1 = *(const float2*)&xpb[1 * RNN_H];
  float2 p2 = *(const float2*)&xpb[2 * RNN_H];
  float2 p3 = *(const float2*)&xpb[3 * RNN_H];

  float hfA = 0.f, hfB = 0.f;

#pragma unroll 1
  for (int t = 0; t < RNN_S; t += 4) {
    const int n0 = (t + 4 < RNN_S) ? t + 4 : RNN_S - 1;
    const int n1 = (t + 5 < RNN_S) ? t + 5 : RNN_S - 1;
    const int n2 = (t + 6 < RNN_S) ? t + 6 : RNN_S - 1;
    const int n3 = (t + 7 < RNN_S) ? t + 7 : RNN_S - 1;
    RNN_STEP1(p0, n0)
    RNN_STEP1(p1, n1)
    RNN_STEP1(p2, n2)
    RNN_STEP1(p3, n3)
  }

  // fused FC using the final-step fp32 h values (hfA/hfB, un-quantized):
  // per-lane partials -> LDS -> lanes 0..2 reduce 64 values each.
#pragma unroll
  for (int o = 0; o < RNN_OUT; ++o) {
    const float2 wf = *(const float2*)&Wfc[(size_t)o * RNN_H + 2 * j];
    fcred[o][j] = wf.x * hfA + wf.y * hfB;
  }
  asm volatile("s_waitcnt lgkmcnt(0)" ::: "memory");
  if (j < RNN_OUT) {
    float s = bfc[j];
#pragma unroll 8
    for (int k = 0; k < 64; ++k) s += fcred[j][k];
    out[b * RNN_OUT + j] = s;
  }
}

extern "C" void kernel_launch(void* const* d_in, const int* in_sizes, int n_in,
                              void* d_out, int out_size, void* d_ws, size_t ws_size,
                              hipStream_t stream) {
  const float* x   = (const float*)d_in[0];
  const float* Wxh = (const float*)d_in[1];
  const float* bxh = (const float*)d_in[2];
  const float* Whh = (const float*)d_in[3];
  const float* bhh = (const float*)d_in[4];
  const float* bh  = (const float*)d_in[5];
  const float* Wfc = (const float*)d_in[6];
  const float* bfc = (const float*)d_in[7];
  float* out = (float*)d_out;
  float* xp  = (float*)d_ws;  // 131072*128*4 = 64 MiB

  xproj_mfma<<<dim3((RNN_B * RNN_S) / 128), dim3(256), 0, stream>>>(x, Wxh, bxh, xp);
  rnn_scan<<<dim3(RNN_B), dim3(64), 0, stream>>>(xp, Whh, bhh, bh, Wfc, bfc, out);
}